// Round 1
// baseline (508.884 us; speedup 1.0000x reference)
//
#include <hip/hip_runtime.h>
#include <math.h>

#define BATCH 16384
#define INPUT_DIM 512
#define HIDDEN 1024
#define NROT 32
#define NANG 496   // 32*31/2

// ---------------------------------------------------------------------------
// GEMM (NT): C[M,N] = epilogue(A[M,K] @ B[N,K]^T + bias[N])
//   EPI=0: relu, store float C[M,N]
//   EPI=1: sincos, store float2 {cos,sin} at C2[M,N] (N guarded, N=496)
// BM=128, BN=64, BK=32, 256 threads, 8x4 micro-tile per thread.
// ---------------------------------------------------------------------------
template<int EPI>
__global__ __launch_bounds__(256) void gemm_nt_kernel(
    const float* __restrict__ A, const float* __restrict__ B,
    const float* __restrict__ bias, float* __restrict__ C,
    int M, int N, int K)
{
    constexpr int BM = 128, BN = 64, BK = 32;
    __shared__ float As[BK][BM + 4];   // +4 keeps rows 16B-aligned for b128 reads
    __shared__ float Bs[BK][BN + 4];

    const int tid = threadIdx.x;
    const int tx = tid & 15;   // col group: cols tx*4 .. tx*4+3
    const int ty = tid >> 4;   // row group: rows ty*8 .. ty*8+7
    const int m0 = blockIdx.y * BM;
    const int n0 = blockIdx.x * BN;

    float acc[8][4];
    #pragma unroll
    for (int m = 0; m < 8; ++m)
        #pragma unroll
        for (int n = 0; n < 4; ++n) acc[m][n] = 0.f;

    for (int k0 = 0; k0 < K; k0 += BK) {
        // ---- stage A tile: 128x32 floats = 1024 float4, 4 per thread ----
        #pragma unroll
        for (int l = 0; l < 4; ++l) {
            int f = tid + l * 256;
            int row = f >> 3;          // 0..127
            int kq  = f & 7;           // 0..7 (float4 along K)
            const float4 v = *(const float4*)(A + (size_t)(m0 + row) * K + k0 + kq * 4);
            As[kq * 4 + 0][row] = v.x;
            As[kq * 4 + 1][row] = v.y;
            As[kq * 4 + 2][row] = v.z;
            As[kq * 4 + 3][row] = v.w;
        }
        // ---- stage B tile: 64x32 floats = 512 float4, 2 per thread ----
        #pragma unroll
        for (int l = 0; l < 2; ++l) {
            int f = tid + l * 256;
            int row = f >> 3;          // 0..63
            int kq  = f & 7;
            float4 v = make_float4(0.f, 0.f, 0.f, 0.f);
            if (EPI == 0 || (n0 + row) < N)
                v = *(const float4*)(B + (size_t)(n0 + row) * K + k0 + kq * 4);
            Bs[kq * 4 + 0][row] = v.x;
            Bs[kq * 4 + 1][row] = v.y;
            Bs[kq * 4 + 2][row] = v.z;
            Bs[kq * 4 + 3][row] = v.w;
        }
        __syncthreads();

        #pragma unroll
        for (int kk = 0; kk < BK; ++kk) {
            float a[8], b[4];
            #pragma unroll
            for (int m = 0; m < 8; ++m) a[m] = As[kk][ty * 8 + m];
            #pragma unroll
            for (int n = 0; n < 4; ++n) b[n] = Bs[kk][tx * 4 + n];
            #pragma unroll
            for (int m = 0; m < 8; ++m)
                #pragma unroll
                for (int n = 0; n < 4; ++n)
                    acc[m][n] = fmaf(a[m], b[n], acc[m][n]);
        }
        __syncthreads();
    }

    if (EPI == 0) {
        // relu(acc + bias), float4 stores (N=1024, always in-bounds)
        const int gn = n0 + tx * 4;
        float4 bb = *(const float4*)(bias + gn);
        #pragma unroll
        for (int m = 0; m < 8; ++m) {
            const int gm = m0 + ty * 8 + m;
            float4 o;
            o.x = fmaxf(acc[m][0] + bb.x, 0.f);
            o.y = fmaxf(acc[m][1] + bb.y, 0.f);
            o.z = fmaxf(acc[m][2] + bb.z, 0.f);
            o.w = fmaxf(acc[m][3] + bb.w, 0.f);
            *(float4*)(C + (size_t)gm * N + gn) = o;
        }
    } else {
        // angles -> (cos, sin) interleaved float2, guarded at N=496
        #pragma unroll
        for (int m = 0; m < 8; ++m) {
            const int gm = m0 + ty * 8 + m;
            #pragma unroll
            for (int n = 0; n < 4; ++n) {
                const int gn = n0 + tx * 4 + n;
                if (gn < N) {
                    float ang = acc[m][n] + bias[gn];
                    float s, c;
                    __sincosf(ang, &s, &c);
                    *(float2*)(C + ((size_t)gm * N + gn) * 2) = make_float2(c, s);
                }
            }
        }
    }
}

// ---------------------------------------------------------------------------
// Givens rotation chain. Each thread owns one row r of one batch element's R
// (32 floats in registers). All 496 (i,j) pairs are compile-time constants
// after full unroll, so v[] stays in registers.
// Block: 256 threads = 8 batch elements x 32 rows. cos/sin staged in LDS.
// ---------------------------------------------------------------------------
__global__ __launch_bounds__(256) void rotate_kernel(
    const float2* __restrict__ cs, float* __restrict__ out)
{
    __shared__ float2 lcs[8][NANG];   // 31,744 B

    const int tid = threadIdx.x;
    const size_t b0 = (size_t)blockIdx.x * 8;

    float2* flat = &lcs[0][0];
    for (int t = tid; t < 8 * NANG; t += 256)
        flat[t] = cs[b0 * NANG + t];
    __syncthreads();

    const int bl = tid >> 5;   // batch element within block
    const int r  = tid & 31;   // row of R

    float v[NROT];
    #pragma unroll
    for (int c = 0; c < NROT; ++c) v[c] = (c == r) ? 1.f : 0.f;

    const float2* mycs = lcs[bl];
    int k = 0;
    #pragma unroll
    for (int i = 0; i < NROT - 1; ++i) {
        #pragma unroll
        for (int j = i + 1; j < NROT; ++j) {
            const float2 t2 = mycs[k];   // (cos, sin), broadcast read
            const float vi = v[i], vj = v[j];
            v[i] = fmaf(t2.x, vi,  t2.y * vj);
            v[j] = fmaf(t2.x, vj, -t2.y * vi);
            ++k;
        }
    }

    float* op = out + ((b0 + bl) * (NROT * NROT) + (size_t)r * NROT);
    #pragma unroll
    for (int q = 0; q < 8; ++q)
        *(float4*)(op + q * 4) = make_float4(v[q*4], v[q*4+1], v[q*4+2], v[q*4+3]);
}

// ---------------------------------------------------------------------------
extern "C" void kernel_launch(void* const* d_in, const int* in_sizes, int n_in,
                              void* d_out, int out_size, void* d_ws, size_t ws_size,
                              hipStream_t stream)
{
    const float* x  = (const float*)d_in[0];   // [16384, 512]
    const float* W1 = (const float*)d_in[1];   // [1024, 512]
    const float* b1 = (const float*)d_in[2];   // [1024]
    const float* W2 = (const float*)d_in[3];   // [496, 1024]
    const float* b2 = (const float*)d_in[4];   // [496]
    float* out = (float*)d_out;                // [16384, 32, 32]

    // d_out (16384*1024 floats) exactly fits h (16384*1024) -> reuse as scratch.
    float* h  = out;
    float* cs = (float*)d_ws;                  // [16384][496][2] = 65 MB

    dim3 blk(256);

    // h = relu(x @ W1^T + b1)
    gemm_nt_kernel<0><<<dim3(HIDDEN / 64, BATCH / 128), blk, 0, stream>>>(
        x, W1, b1, h, BATCH, HIDDEN, INPUT_DIM);

    // cs = (cos, sin)(h @ W2^T + b2)
    gemm_nt_kernel<1><<<dim3((NANG + 63) / 64, BATCH / 128), blk, 0, stream>>>(
        h, W2, b2, cs, BATCH, NANG, HIDDEN);

    // R = product of Givens rotations applied to identity
    rotate_kernel<<<dim3(BATCH / 8), blk, 0, stream>>>((const float2*)cs, out);
}

// Round 2
// 151.729 us; speedup vs baseline: 3.3539x; 3.3539x over previous
//
#include <hip/hip_runtime.h>
#include <math.h>

#define BATCH 16384
#define INPUT_DIM 512
#define HIDDEN 1024
#define NROT 32
#define NANG 496   // 32*31/2

typedef _Float16 half8 __attribute__((ext_vector_type(8)));
typedef float    f32x4 __attribute__((ext_vector_type(4)));

// ---------------------------------------------------------------------------
// Split-precision f16 MFMA GEMM (NT): C = epi(A[M,K] @ B[N,K]^T + bias)
// A = Ah + Al (f16 residual split, 2 MFMA passes); B rounded to f16.
// Tile 128x128xBK32, 4 waves (2x2), each wave 64x64 via mfma_f32_16x16x32_f16.
// LDS XOR-swizzled (chunk ^= row&3) -> conflict-free ds_write_b128/ds_read_b128.
// Double-buffered; next-tile global loads issued before barrier (latency hide).
//   EPI=0: relu(acc+bias) -> float C[M][Nout]
//   EPI=1: sincos(acc+bias) -> float2 C[M][Nout], col guarded (< Nout)
// ---------------------------------------------------------------------------
template<int EPI>
__global__ __launch_bounds__(256) void gemm_nt_mfma(
    const float* __restrict__ A, const float* __restrict__ B,
    const float* __restrict__ bias, float* __restrict__ C,
    int M, int N, int K, int Nout)
{
    constexpr int BK = 32;                    // K per stage (f32 elems)
    __shared__ _Float16 sAh[2][128 * BK];     // 8 KB each buf
    __shared__ _Float16 sAl[2][128 * BK];
    __shared__ _Float16 sB [2][128 * BK];     // total 48 KB

    const int tid = threadIdx.x;
    const int m0 = blockIdx.y * 128;
    const int n0 = blockIdx.x * 128;

    // --- staging: thread owns chunk (row=tid>>2, k8=tid&3) and (row+64, k8)
    //     for both A and B; chunk = 8 consecutive f32 along K.
    const int rA  = tid >> 2;                       // 0..63
    const int k8  = tid & 3;
    const int swW = ((k8 ^ (rA & 3)) << 3);         // swizzled f16 offset in row

    float4 rg[4][2];    // [A row rA][A row rA+64][B row rA][B row rA+64]

    auto load_tile = [&](int kt) {
        const size_t koff = (size_t)kt * BK + k8 * 8;
        const float4* p;
        p = (const float4*)(A + (size_t)(m0 + rA) * K + koff);
        rg[0][0] = p[0]; rg[0][1] = p[1];
        p = (const float4*)(A + (size_t)(m0 + rA + 64) * K + koff);
        rg[1][0] = p[0]; rg[1][1] = p[1];
        const float4 z = make_float4(0.f, 0.f, 0.f, 0.f);
        if (EPI == 0 || (n0 + rA) < N) {
            p = (const float4*)(B + (size_t)(n0 + rA) * K + koff);
            rg[2][0] = p[0]; rg[2][1] = p[1];
        } else { rg[2][0] = z; rg[2][1] = z; }
        if (EPI == 0 || (n0 + rA + 64) < N) {
            p = (const float4*)(B + (size_t)(n0 + rA + 64) * K + koff);
            rg[3][0] = p[0]; rg[3][1] = p[1];
        } else { rg[3][0] = z; rg[3][1] = z; }
    };

    auto cvt_write = [&](int buf) {
        #pragma unroll
        for (int h = 0; h < 2; ++h) {
            const int base = (rA + h * 64) * BK + swW;
            half8 hi, lo;
            const float* f = (const float*)&rg[h][0];
            #pragma unroll
            for (int j = 0; j < 8; ++j) {
                _Float16 hv = (_Float16)f[j];
                hi[j] = hv;
                lo[j] = (_Float16)(f[j] - (float)hv);
            }
            *(half8*)&sAh[buf][base] = hi;
            *(half8*)&sAl[buf][base] = lo;
        }
        #pragma unroll
        for (int h = 0; h < 2; ++h) {
            const int base = (rA + h * 64) * BK + swW;
            half8 bv;
            const float* f = (const float*)&rg[2 + h][0];
            #pragma unroll
            for (int j = 0; j < 8; ++j) bv[j] = (_Float16)f[j];
            *(half8*)&sB[buf][base] = bv;
        }
    };

    // --- compute-side fragment addressing
    const int lane = tid & 63;
    const int wid  = tid >> 6;
    const int wr = wid >> 1, wc = wid & 1;          // wave -> 64x64 sub-tile
    const int fr = lane & 15, fq = lane >> 4;
    const int swR   = ((fq ^ (fr & 3)) << 3);
    const int aBase = (wr * 64 + fr) * BK + swR;
    const int bBase = (wc * 64 + fr) * BK + swR;

    f32x4 acc[4][4];
    #pragma unroll
    for (int i = 0; i < 4; ++i)
        #pragma unroll
        for (int j = 0; j < 4; ++j) acc[i][j] = (f32x4)(0.f);

    const int NT = K / BK;
    load_tile(0);
    cvt_write(0);
    int cur = 0;

    for (int kt = 0; kt < NT; ++kt) {
        const bool more = (kt + 1 < NT);
        if (more) load_tile(kt + 1);        // in flight across barrier + MFMA
        __syncthreads();

        half8 ah[4], al[4], bb[4];
        #pragma unroll
        for (int f = 0; f < 4; ++f) {
            ah[f] = *(const half8*)&sAh[cur][aBase + f * 16 * BK];
            al[f] = *(const half8*)&sAl[cur][aBase + f * 16 * BK];
            bb[f] = *(const half8*)&sB [cur][bBase + f * 16 * BK];
        }
        #pragma unroll
        for (int fm = 0; fm < 4; ++fm)
            #pragma unroll
            for (int fn = 0; fn < 4; ++fn) {
                acc[fm][fn] = __builtin_amdgcn_mfma_f32_16x16x32_f16(
                    al[fm], bb[fn], acc[fm][fn], 0, 0, 0);
                acc[fm][fn] = __builtin_amdgcn_mfma_f32_16x16x32_f16(
                    ah[fm], bb[fn], acc[fm][fn], 0, 0, 0);
            }

        if (more) cvt_write(cur ^ 1);       // prev readers of buf^1 done at barrier
        cur ^= 1;
    }

    // --- epilogue: C row = (l>>4)*4+reg, col = l&15 within each 16x16 frag
    if (EPI == 0) {
        #pragma unroll
        for (int fn = 0; fn < 4; ++fn) {
            const int col = n0 + wc * 64 + fn * 16 + fr;
            const float bv = bias[col];
            #pragma unroll
            for (int fm = 0; fm < 4; ++fm) {
                const int row0 = m0 + wr * 64 + fm * 16 + fq * 4;
                #pragma unroll
                for (int r = 0; r < 4; ++r)
                    C[(size_t)(row0 + r) * Nout + col] =
                        fmaxf(acc[fm][fn][r] + bv, 0.f);
            }
        }
    } else {
        #pragma unroll
        for (int fn = 0; fn < 4; ++fn) {
            const int col = n0 + wc * 64 + fn * 16 + fr;
            if (col < Nout) {
                const float bv = bias[col];
                #pragma unroll
                for (int fm = 0; fm < 4; ++fm) {
                    const int row0 = m0 + wr * 64 + fm * 16 + fq * 4;
                    #pragma unroll
                    for (int r = 0; r < 4; ++r) {
                        const float ang = acc[fm][fn][r] + bv;
                        float s, c;
                        __sincosf(ang, &s, &c);
                        *(float2*)(C + ((size_t)(row0 + r) * Nout + col) * 2) =
                            make_float2(c, s);
                    }
                }
            }
        }
    }
}

// ---------------------------------------------------------------------------
// Givens rotation chain: thread = one row of one batch element's R, all 496
// (i,j) pairs compile-time constants -> v[] stays in registers.
// ---------------------------------------------------------------------------
__global__ __launch_bounds__(256) void rotate_kernel(
    const float2* __restrict__ cs, float* __restrict__ out)
{
    __shared__ float2 lcs[8][NANG];   // 31,744 B

    const int tid = threadIdx.x;
    const size_t b0 = (size_t)blockIdx.x * 8;

    float2* flat = &lcs[0][0];
    for (int t = tid; t < 8 * NANG; t += 256)
        flat[t] = cs[b0 * NANG + t];
    __syncthreads();

    const int bl = tid >> 5;
    const int r  = tid & 31;

    float v[NROT];
    #pragma unroll
    for (int c = 0; c < NROT; ++c) v[c] = (c == r) ? 1.f : 0.f;

    const float2* mycs = lcs[bl];
    int k = 0;
    #pragma unroll
    for (int i = 0; i < NROT - 1; ++i) {
        #pragma unroll
        for (int j = i + 1; j < NROT; ++j) {
            const float2 t2 = mycs[k];
            const float vi = v[i], vj = v[j];
            v[i] = fmaf(t2.x, vi,  t2.y * vj);
            v[j] = fmaf(t2.x, vj, -t2.y * vi);
            ++k;
        }
    }

    float* op = out + ((b0 + bl) * (NROT * NROT) + (size_t)r * NROT);
    #pragma unroll
    for (int q = 0; q < 8; ++q)
        *(float4*)(op + q * 4) = make_float4(v[q*4], v[q*4+1], v[q*4+2], v[q*4+3]);
}

// ---------------------------------------------------------------------------
extern "C" void kernel_launch(void* const* d_in, const int* in_sizes, int n_in,
                              void* d_out, int out_size, void* d_ws, size_t ws_size,
                              hipStream_t stream)
{
    const float* x  = (const float*)d_in[0];   // [16384, 512]
    const float* W1 = (const float*)d_in[1];   // [1024, 512]
    const float* b1 = (const float*)d_in[2];   // [1024]
    const float* W2 = (const float*)d_in[3];   // [496, 1024]
    const float* b2 = (const float*)d_in[4];   // [496]
    float* out = (float*)d_out;                // [16384, 32, 32]

    float* h  = out;              // d_out (64 MB) doubles as h scratch
    float* cs = (float*)d_ws;     // [16384][496] float2 = 65 MB

    // h = relu(x @ W1^T + b1)
    gemm_nt_mfma<0><<<dim3(HIDDEN / 128, BATCH / 128), 256, 0, stream>>>(
        x, W1, b1, h, BATCH, HIDDEN, INPUT_DIM, HIDDEN);

    // cs = (cos,sin)(h @ W2^T + b2)
    gemm_nt_mfma<1><<<dim3((NANG + 127) / 128, BATCH / 128), 256, 0, stream>>>(
        h, W2, b2, cs, BATCH, NANG, HIDDEN, NANG);

    // R = Givens chain applied to identity
    rotate_kernel<<<dim3(BATCH / 8), 256, 0, stream>>>((const float2*)cs, out);
}